// Round 7
// baseline (448.278 us; speedup 1.0000x reference)
//
#include <hip/hip_runtime.h>
#include <math.h>

// PointPWC multi-scale loss. B=2, scales N={8192,4096,2048,1024}.
// Inputs (B,3,N) fp32 channel-major. Output: single fp32 scalar.
//
// R15: candidate broadcast via VMEM + v_readlane (SMEM path removed).
// R14 post-mortem: halving SMEM transactions (x8->x16) gave only 5% ->
// the ~2x gap vs static VALU (53.8 vs 28 cyc/unit, true VALU duty 52%)
// is exposed scalar-memory latency: s_load -> lgkmcnt(0) -> compute has
// zero in-wave overlap (SMEM completes OOO so only lgkmcnt(0) is safe),
// and K$ miss contention from 32 waves/CU defeats TLP cover. Fix: each
// lane VMEM-loads one candidate (coalesced, L2-resident, IN-ORDER ->
// counted vmcnt works); 64-cand chunks double-buffered in 6 VGPRs with
// ~2600 cyc of compute covering each prefetch (compiler-managed waits);
// broadcast lane t via __builtin_amdgcn_readlane (runtime lane index).
// readlane result is an SGPR like s_load's was -> v_sub v,s,v dist math
// unchanged -> selection keys bit-identical -> absmax must stay 0.
// Schedule (R13-proven): persistent 1024 blocks; A(340) B(340) C(340)
// heavy tasks then 1360 fine D-micro fillers (atomicMin merge).

#define UNIT 1024
#define NTOT 15360
#define MASKC 0xFFFFE000u
#define NTASK 2380u   // 340 A + 340 B + 340 C + 1360 D-micro

typedef unsigned int uint;

struct Params {
  const float* pc1[4];
  const float* pc2[4];
  const float* fl[4];
  float4* cv2;   // [B][NTOT]
  float4* cvw;   // [B][NTOT]
  float* keys;   // [5][B*NTOT] packed top-5 keys (pass C)
  uint* d2u;     // [B*NTOT] partial mins (pass D)
  uint* cnt;     // task queue counter
  float* warp;   // per-scale [B][3][N] warped p1 (= p1+fl)
  float* out;
};

// ---------- helpers ----------

__device__ __forceinline__ float wave_sum(float v) {
  #pragma unroll
  for (int o = 32; o; o >>= 1) v += __shfl_down(v, o, 64);
  return v;
}

template <int K>
__device__ __forceinline__ void key_insert(float (&kd)[K], float kf) {
  #pragma unroll
  for (int m = K - 1; m >= 1; --m)
    kd[m] = __builtin_amdgcn_fmed3f(kf, kd[m - 1], kd[m]);
  kd[0] = fminf(kd[0], kf);
}

template <int K>
__device__ __forceinline__ void merge_pair(float (&a)[K], const float (&b)[K]) {
  #pragma unroll
  for (int m = 0; m < K; ++m) key_insert<K>(a, b[m]);
}

__device__ __forceinline__ float pack_key_u(float d, uint iw) {
  return __uint_as_float((__float_as_uint(d) & MASKC) | iw);
}

// Broadcast lane t's float to all lanes (lands in SGPR; t may be runtime).
__device__ __forceinline__ float rl(float v, int t) {
  return __uint_as_float(
      (uint)__builtin_amdgcn_readlane((int)__float_as_uint(v), t));
}

// Process 64 candidates held one-per-lane in (cx,cy,cz). Two alternating
// chains (even->a, odd->b): same candidate order as R10..R14 -> same keys.
template <int K, bool MIN>
__device__ __forceinline__ void proc64(float cx, float cy, float cz,
                                       int cbase, float ax, float ay,
                                       float az, float (&a)[K],
                                       float (&b)[K]) {
  #pragma unroll 8
  for (int t = 0; t < 64; t += 2) {
    float xA = rl(cx, t), yA = rl(cy, t), zA = rl(cz, t);
    float xB = rl(cx, t + 1), yB = rl(cy, t + 1), zB = rl(cz, t + 1);
    float dxa = xA - ax, dya = yA - ay, dza = zA - az;
    float dA = fmaf(dxa, dxa, fmaf(dya, dya, dza * dza));
    float dxb = xB - ax, dyb = yB - ay, dzb = zB - az;
    float dB = fmaf(dxb, dxb, fmaf(dyb, dyb, dzb * dzb));
    if (MIN) {
      a[0] = fminf(a[0], dA);
      b[0] = fminf(b[0], dB);
    } else {
      key_insert<K>(a, pack_key_u(dA, (uint)(cbase + t)));
      key_insert<K>(b, pack_key_u(dB, (uint)(cbase + t + 1)));
    }
  }
}

// Scan [lo, lo+len): 64-cand chunks, double-buffered VGPR staging. len is
// a multiple of 128. The next-chunk loads sit ~2600 VALU-cycles ahead of
// their first use (compiler inserts the vmcnt) -> latency fully hidden.
template <int K, bool MIN>
__device__ void scan(const float* px, const float* py, const float* pz,
                     int lo, int len, int lane, float ax, float ay,
                     float az, float (&a)[K], float (&b)[K]) {
  int j = lo + lane;
  float cx0 = px[j], cy0 = py[j], cz0 = pz[j];
  #pragma unroll 1
  for (int c0 = 0; c0 < len; c0 += 128) {
    int j1 = j + 64;
    float cx1 = px[j1], cy1 = py[j1], cz1 = pz[j1];
    proc64<K, MIN>(cx0, cy0, cz0, lo + c0, ax, ay, az, a, b);
    int j2 = (c0 + 128 < len) ? j + 128 : j;   // clamp: harmless reload
    cx0 = px[j2]; cy0 = py[j2]; cz0 = pz[j2];
    proc64<K, MIN>(cx1, cy1, cz1, lo + c0 + 64, ax, ay, az, a, b);
    j += 128;
  }
}

// r in [0,340) -> scale s, batch b, query-group base i0, candidate lo.
// Only i0/lo depend on wv; s,b are block-uniform.
__device__ __forceinline__ void decode(int r, int wv, int& s, int& b,
                                       int& i0, int& lo, int& N, int& cpw,
                                       int& off, float& alpha) {
  int rr;
  if (r < 256)      { s = 0; rr = r; }
  else if (r < 320) { s = 1; rr = r - 256; }
  else if (r < 336) { s = 2; rr = r - 320; }
  else              { s = 3; rr = r - 336; }
  N = 8192 >> s;
  cpw = 8 >> s;
  int perb = 128 >> (2 * s);
  b = rr >> (7 - 2 * s);
  int chunk = rr & (perb - 1);
  int qg = (chunk << s) + (wv >> (3 - s));
  i0 = qg << 6;
  lo = (wv & (cpw - 1)) << 10;
  off = 16384 - (16384 >> s);
  alpha = 0.02f * (float)(1 << s);
}

// Stage per-thread list; group leader (wave with cr==0) merges its
// qgroup's cpw lists. Returns true for leader threads.
template <int K>
__device__ __forceinline__ bool merge_group(float (&a)[K], float* sm,
                                            int tid, int cpw) {
  const int STR = K | 1;   // odd stride: 2-way bank aliasing only (free)
  int q = tid & 63, wv = tid >> 6;
  #pragma unroll
  for (int m = 0; m < K; ++m) sm[(wv * 64 + q) * STR + m] = a[m];
  __syncthreads();
  if (wv & (cpw - 1)) return false;
  for (int w = wv + 1; w < wv + cpw; ++w)
    #pragma unroll
    for (int m = 0; m < K; ++m)
      key_insert<K>(a, sm[(w * 64 + q) * STR + m]);
  return true;
}

// ---------- kernels ----------

// Init scalars/d2u AND precompute warp = p1+fl (flat per scale; same
// rounding as the p1[j]+fl[j] it replaces -> bit-identical).
__global__ __launch_bounds__(256) void k_init(Params P) {
  int t = blockIdx.x * 256 + threadIdx.x;
  if (t == 0) { P.out[0] = 0.f; *P.cnt = 1024u; }   // first tasks static
  if (t < 2 * NTOT) P.d2u[t] = 0x7F7FFFFFu;         // FLT_MAX bits
  int s, r;
  if (t < 49152)      { s = 0; r = t; }
  else if (t < 73728) { s = 1; r = t - 49152; }
  else if (t < 86016) { s = 2; r = t - 73728; }
  else if (t < 92160) { s = 3; r = t - 86016; }
  else return;
  int base6 = (s == 0) ? 0 : (s == 1) ? 49152 : (s == 2) ? 73728 : 86016;
  P.warp[base6 + r] = P.pc1[s][r] + P.fl[s][r];
}

// Persistent blocks; task t: [0,340) A, [340,680) B, [680,1020) C,
// [1020,2380) D-micro. D-micro: (s,b) from t ONLY; 8 waves split
// within-batch wave-units u = ti*8 + wv (counts 4096/1024/256/64, /8).
__global__ __launch_bounds__(512, 8) void k_work(Params P) {
  __shared__ float sm[8 * 64 * 11];   // 22.5 KB merge staging
  __shared__ uint ts;
  int tid = threadIdx.x, q = tid & 63, wv = tid >> 6;

  uint t = blockIdx.x;                // static first task, no pop burst
  while (t < NTASK) {
    if (t < 1020u) {
      int pass = (int)t / 340, r = (int)t % 340;
      int s, b, i0, lo, N, cpw, off; float alpha;
      decode(r, wv, s, b, i0, lo, N, cpw, off, alpha);
      int i = i0 + q;
      int lo_u = __builtin_amdgcn_readfirstlane(lo);

      if (pass == 0) {            // A: p2 self top-10 -> cv2
        const float* p2 = P.pc2[s] + b * 3 * N;
        float ax = p2[i], ay = p2[N + i], az = p2[2 * N + i];
        float a[10], bb[10];
        #pragma unroll
        for (int m = 0; m < 10; ++m) { a[m] = 3.0e38f; bb[m] = 3.0e38f; }
        scan<10, false>(p2, p2 + N, p2 + 2 * N, lo_u, UNIT, q,
                        ax, ay, az, a, bb);
        merge_pair<10>(a, bb);
        if (merge_group<10>(a, sm, tid, cpw)) {
          float sx = 0.f, sy = 0.f, sz = 0.f;
          #pragma unroll
          for (int m = 0; m < 10; ++m) {
            int j = (int)(__float_as_uint(a[m]) & 0x1FFFu);
            sx += p2[j]; sy += p2[N + j]; sz += p2[2 * N + j];
          }
          const float inv9 = 1.f / 9.f;
          P.cv2[b * NTOT + off + i] = make_float4((sx - 10.f * ax) * inv9,
                                                  (sy - 10.f * ay) * inv9,
                                                  (sz - 10.f * az) * inv9,
                                                  0.f);
        }
      } else if (pass == 1) {     // B: p1 self top-10 -> cvw + smooth
        const float* p1 = P.pc1[s] + b * 3 * N;
        const float* fl = P.fl[s] + b * 3 * N;
        float ax = p1[i], ay = p1[N + i], az = p1[2 * N + i];
        float a[10], bb[10];
        #pragma unroll
        for (int m = 0; m < 10; ++m) { a[m] = 3.0e38f; bb[m] = 3.0e38f; }
        scan<10, false>(p1, p1 + N, p1 + 2 * N, lo_u, UNIT, q,
                        ax, ay, az, a, bb);
        merge_pair<10>(a, bb);
        if (merge_group<10>(a, sm, tid, cpw)) {
          float fix = fl[i], fiy = fl[N + i], fiz = fl[2 * N + i];
          float wix = ax + fix, wiy = ay + fiy, wiz = az + fiz;
          float sx = 0.f, sy = 0.f, sz = 0.f, smooth = 0.f;
          float dmax = -1.f, worst = 0.f;
          #pragma unroll
          for (int m = 0; m < 10; ++m) {
            int j = (int)(__float_as_uint(a[m]) & 0x1FFFu);
            float px = p1[j], py = p1[N + j], pz = p1[2 * N + j];
            float flx = fl[j], fly = fl[N + j], flz = fl[2 * N + j];
            sx += px + flx; sy += py + fly; sz += pz + flz;
            float ddx = px - ax, ddy = py - ay, ddz = pz - az;
            float d = fmaf(ddx, ddx, fmaf(ddy, ddy, ddz * ddz));  // exact
            float gx = flx - fix, gy = fly - fiy, gz = flz - fiz;
            float term = sqrtf(fmaf(gx, gx, fmaf(gy, gy, gz * gz)));
            smooth += term;
            if (d > dmax) { dmax = d; worst = term; }  // drop farthest (k9)
          }
          smooth -= worst;
          const float inv9 = 1.f / 9.f;
          P.cvw[b * NTOT + off + i] = make_float4((sx - 10.f * wix) * inv9,
                                                  (sy - 10.f * wiy) * inv9,
                                                  (sz - 10.f * wiz) * inv9,
                                                  0.f);
          float ssum = wave_sum(smooth * (1.f / 8.f));
          if (q == 0) atomicAdd(P.out, alpha * 0.5f * ssum);
        }
      } else {                    // C: warp -> p2 top-5 -> packed keys
        int base6 = (s == 0) ? 0 : (s == 1) ? 49152 : (s == 2) ? 73728
                                                               : 86016;
        const float* wq = P.warp + base6 + b * 3 * N;
        const float* p2 = P.pc2[s] + b * 3 * N;
        float ax = wq[i], ay = wq[N + i], az = wq[2 * N + i];  // == p1+fl
        float a[5], bb[5];
        #pragma unroll
        for (int m = 0; m < 5; ++m) { a[m] = 3.0e38f; bb[m] = 3.0e38f; }
        scan<5, false>(p2, p2 + N, p2 + 2 * N, lo_u, UNIT, q,
                       ax, ay, az, a, bb);
        merge_pair<5>(a, bb);
        if (merge_group<5>(a, sm, tid, cpw)) {
          #pragma unroll
          for (int m = 0; m < 5; ++m)
            P.keys[m * (2 * NTOT) + b * NTOT + off + i] = a[m];
        }
      }
    } else {                      // D-micro: p2 -> warp min, atomicMin
      int dm = (int)(t - 1020u);
      int s, tb;
      if (dm < 1024)      { s = 0; tb = dm; }
      else if (dm < 1280) { s = 1; tb = dm - 1024; }
      else if (dm < 1344) { s = 2; tb = dm - 1280; }
      else                { s = 3; tb = dm - 1344; }
      int N = 8192 >> s;
      int tpb = 512 >> (2 * s);            // tasks per batch
      int b = tb >> (9 - 2 * s);           // tb / tpb
      int ti = tb & (tpb - 1);
      int u = ti * 8 + wv;                 // wave-unit within batch
      int rpq = 32 >> s;                   // 256-ranges per qgroup
      int qg = u >> (5 - s);               // u / rpq
      int rg = u & (rpq - 1);
      int i = qg * 64 + q, lo = rg * 256;
      int off = 16384 - (16384 >> s);
      int base6 = (s == 0) ? 0 : (s == 1) ? 49152 : (s == 2) ? 73728
                                                             : 86016;
      const float* wc = P.warp + base6 + b * 3 * N;  // block-uniform
      const float* p2 = P.pc2[s] + b * 3 * N;
      float ax = p2[i], ay = p2[N + i], az = p2[2 * N + i];
      float a0[1], b0[1];
      a0[0] = 3.0e38f; b0[0] = 3.0e38f;
      int lo_u = __builtin_amdgcn_readfirstlane(lo);
      scan<1, true>(wc, wc + N, wc + 2 * N, lo_u, 256, q,
                    ax, ay, az, a0, b0);
      atomicMin(P.d2u + b * NTOT + off + i,
                __float_as_uint(fminf(a0[0], b0[0])));
    }
    __syncthreads();              // sm + ts reuse safety
    if (tid == 0) ts = atomicAdd(P.cnt, 1u);
    __syncthreads();
    t = ts;
  }
}

// Epilogue: C top-5 -> dist1 + inverse-distance cv2 interp -> curvature;
// plus D partial-min sum. 30720 threads.
__global__ __launch_bounds__(256) void k_epi(Params P) {
  int t = blockIdx.x * 256 + threadIdx.x;   // [0, 2*NTOT)
  int b = t >= NTOT;
  int r = t - b * NTOT;
  int s, i;
  if (r < 8192)       { s = 0; i = r; }
  else if (r < 12288) { s = 1; i = r - 8192; }
  else if (r < 14336) { s = 2; i = r - 12288; }
  else                { s = 3; i = r - 14336; }
  int N = 8192 >> s;
  int off = 16384 - (16384 >> s);
  float alpha = 0.02f * (float)(1 << s);
  const float* p1 = P.pc1[s] + b * 3 * N;
  const float* fl = P.fl[s] + b * 3 * N;
  const float* p2 = P.pc2[s] + b * 3 * N;
  float ax = p1[i] + fl[i], ay = p1[N + i] + fl[N + i],
        az = p1[2 * N + i] + fl[2 * N + i];
  float dist1 = 3.0e38f, wsum = 0.f, ix = 0.f, iy = 0.f, iz = 0.f;
  #pragma unroll
  for (int m = 0; m < 5; ++m) {
    uint key = __float_as_uint(P.keys[m * (2 * NTOT) + b * NTOT + off + i]);
    int j = (int)(key & 0x1FFFu);
    float px = p2[j], py = p2[N + j], pz = p2[2 * N + j];
    float ddx = px - ax, ddy = py - ay, ddz = pz - az;
    float d = fmaf(ddx, ddx, fmaf(ddy, ddy, ddz * ddz));  // exact
    dist1 = fminf(dist1, d);
    float w = 1.f / (d + 1e-8f);
    wsum += w;
    float4 cv = P.cv2[b * NTOT + off + j];
    ix += w * cv.x; iy += w * cv.y; iz += w * cv.z;
  }
  float inv = 1.f / wsum;
  ix *= inv; iy *= inv; iz *= inv;
  float4 cw = P.cvw[b * NTOT + off + i];
  float ex = ix - cw.x, ey = iy - cw.y, ez = iz - cw.z;
  float curv = fmaf(ex, ex, fmaf(ey, ey, ez * ez));
  float csum = wave_sum(dist1 + 0.3f * curv);
  float msum = wave_sum(__uint_as_float(P.d2u[t]));
  if ((threadIdx.x & 63) == 0) {
    atomicAdd(P.out, alpha * 0.5f * csum);
    atomicAdd(P.out, alpha * 0.5f * msum);
  }
}

extern "C" void kernel_launch(void* const* d_in, const int* in_sizes, int n_in,
                              void* d_out, int out_size, void* d_ws,
                              size_t ws_size, hipStream_t stream) {
  Params P;
  for (int s = 0; s < 4; ++s) {
    P.pc1[s] = (const float*)d_in[s];
    P.pc2[s] = (const float*)d_in[4 + s];
    P.fl[s]  = (const float*)d_in[8 + s];
  }
  char* ws = (char*)d_ws;
  P.cv2  = (float4*)ws;                    // 491520 B
  P.cvw  = (float4*)(ws + 491520);         // 491520 B
  P.keys = (float*)(ws + 983040);          // 614400 B
  P.d2u  = (uint*)(ws + 1597440);          // 122880 B
  P.cnt  = (uint*)(ws + 1720320);          // 64 B
  P.warp = (float*)(ws + 1720384);         // 368640 B (total 2089024)
  P.out  = (float*)d_out;

  k_init<<<dim3(360), dim3(256), 0, stream>>>(P);
  k_work<<<dim3(1024), dim3(512), 0, stream>>>(P);
  k_epi<<<dim3(120), dim3(256), 0, stream>>>(P);
}

// Round 8
// 396.705 us; speedup vs baseline: 1.1300x; 1.1300x over previous
//
#include <hip/hip_runtime.h>
#include <math.h>

// PointPWC multi-scale loss. B=2, scales N={8192,4096,2048,1024}.
// Inputs (B,3,N) fp32 channel-major. Output: single fp32 scalar.
//
// R16 = R14 (best, 244us k_work) + instruction-count cut.
// R15 lesson: readlane broadcast adds VALU->SGPR hazard nops (-58%); SMEM
// x16 broadcast stays. R14 lesson: per-unit cost is ~proportional to
// instr count + fixed overhead -> cut instructions:
//  1. Candidates packed float4 {x,y,z,|c|^2} (k_init); ONE SMEM stream,
//     4x s_load_dwordx16 per 16-cand chunk.
//  2. Dot-form distance, exactness-preserving: d'' = fma(-2q, c, Q2)+C2
//     with Q2=|q|^2 as fma seed (every op <=1 SGPR operand). d'' = d +-
//     ~1e-6 abs; quantized-key order preserved (boundary gaps ~1e-3).
//     Reference itself computes d in dot form. Epilogues recompute exact
//     d from indices as before.
//  3. 1-op pack: v_and_or_b32 key, d, vmask(VGPR), idx(SGPR).
// Per-pair VALU: A/B 18->15, C 13->10, D 7->5.
// Schedule (R13-proven): persistent 1024 blocks; A(340) B(340) C(340)
// then 1360 fine D-micro fillers (atomicMin; uint order==float order).

#define UNIT 1024
#define NTOT 15360
#define MASKC 0xFFFFE000u
#define NTASK 2380u   // 340 A + 340 B + 340 C + 1360 D-micro

typedef unsigned int uint;
typedef __attribute__((ext_vector_type(16))) float f16v;

struct Params {
  const float* pc1[4];
  const float* pc2[4];
  const float* fl[4];
  float4* cv2;   // [B][NTOT]
  float4* cvw;   // [B][NTOT]
  float* keys;   // [5][B*NTOT] packed top-5 keys (pass C)
  uint* d2u;     // [B*NTOT] partial mins (pass D)
  uint* cnt;     // task queue counter
  float4* p2pk;  // [B*NTOT] {x,y,z,|c|2} of pc2
  float4* p1pk;  // [B*NTOT] {x,y,z,|c|2} of pc1
  float4* wpk;   // [B*NTOT] {x,y,z,|c|2} of warp = p1+fl
  float* out;
};

// ---------- helpers ----------

__device__ __forceinline__ float wave_sum(float v) {
  #pragma unroll
  for (int o = 32; o; o >>= 1) v += __shfl_down(v, o, 64);
  return v;
}

template <int K>
__device__ __forceinline__ void key_insert(float (&kd)[K], float kf) {
  #pragma unroll
  for (int m = K - 1; m >= 1; --m)
    kd[m] = __builtin_amdgcn_fmed3f(kf, kd[m - 1], kd[m]);
  kd[0] = fminf(kd[0], kf);
}

template <int K>
__device__ __forceinline__ void merge_pair(float (&a)[K], const float (&b)[K]) {
  #pragma unroll
  for (int m = 0; m < K; ++m) key_insert<K>(a, b[m]);
}

// Wave-uniform broadcast of 16 packed candidates (64 dwords) into SGPRs.
// Loads + waitcnt fused in ONE asm block (SMEM completes out-of-order;
// counted lgkm waits unsafe). cp must be block-uniform.
__device__ __forceinline__ void sload16c(const float4* cp, int boff,
                                         f16v& r0, f16v& r1, f16v& r2,
                                         f16v& r3) {
  asm volatile(
      "s_load_dwordx16 %0, %4, %5\n\t"
      "s_load_dwordx16 %1, %4, %6\n\t"
      "s_load_dwordx16 %2, %4, %7\n\t"
      "s_load_dwordx16 %3, %4, %8\n\t"
      "s_waitcnt lgkmcnt(0)"
      : "=&s"(r0), "=&s"(r1), "=&s"(r2), "=&s"(r3)
      : "s"(cp), "s"(boff), "s"(boff + 64), "s"(boff + 128),
        "s"(boff + 192));
}

// 16 candidates from 4 SGPR-resident float4x4 registers. Two chains.
// d'' = fma(m2x,X, fma(m2y,Y, fma(m2z,Z, Q2))) + C2  (<=1 SGPR per op).
template <int K, bool MIN>
__device__ __forceinline__ void do16(const f16v& r0, const f16v& r1,
                                     const f16v& r2, const f16v& r3,
                                     int cbase, float m2x, float m2y,
                                     float m2z, float q2, uint vmask,
                                     float (&a)[K], float (&b)[K]) {
  #pragma unroll
  for (int t = 0; t < 16; t += 2) {
    const f16v& r = (t < 4) ? r0 : (t < 8) ? r1 : (t < 12) ? r2 : r3;
    int eA = (t & 3) * 4, eB = eA + 4;
    float dA = fmaf(m2x, r[eA], q2);
    dA = fmaf(m2y, r[eA + 1], dA);
    dA = fmaf(m2z, r[eA + 2], dA);
    dA = r[eA + 3] + dA;
    float dB = fmaf(m2x, r[eB], q2);
    dB = fmaf(m2y, r[eB + 1], dB);
    dB = fmaf(m2z, r[eB + 2], dB);
    dB = r[eB + 3] + dB;
    if (MIN) {
      a[0] = fminf(a[0], dA);
      b[0] = fminf(b[0], dB);
    } else {
      uint idxA = (uint)(cbase + t), idxB = idxA + 1u;
      uint kA, kB;
      asm("v_and_or_b32 %0, %1, %2, %3"
          : "=v"(kA)
          : "v"(__float_as_uint(dA)), "v"(vmask), "s"(idxA));
      asm("v_and_or_b32 %0, %1, %2, %3"
          : "=v"(kB)
          : "v"(__float_as_uint(dB)), "v"(vmask), "s"(idxB));
      key_insert<K>(a, __uint_as_float(kA));
      key_insert<K>(b, __uint_as_float(kB));
    }
  }
}

// Scan [lo, lo+len) over packed candidate array cp (block-uniform).
template <int K, bool MIN>
__device__ void scan_dot(const float4* cp, int lo, int len, float m2x,
                         float m2y, float m2z, float q2, uint vmask,
                         float (&a)[K], float (&b)[K]) {
  #pragma unroll 1
  for (int c0 = 0; c0 < len; c0 += 16) {
    f16v r0, r1, r2, r3;
    sload16c(cp, (lo + c0) * 16, r0, r1, r2, r3);
    do16<K, MIN>(r0, r1, r2, r3, lo + c0, m2x, m2y, m2z, q2, vmask, a, b);
  }
}

// r in [0,340) -> scale s, batch b, query-group base i0, candidate lo.
// Only i0/lo depend on wv; s,b are block-uniform.
__device__ __forceinline__ void decode(int r, int wv, int& s, int& b,
                                       int& i0, int& lo, int& N, int& cpw,
                                       int& off, float& alpha) {
  int rr;
  if (r < 256)      { s = 0; rr = r; }
  else if (r < 320) { s = 1; rr = r - 256; }
  else if (r < 336) { s = 2; rr = r - 320; }
  else              { s = 3; rr = r - 336; }
  N = 8192 >> s;
  cpw = 8 >> s;
  int perb = 128 >> (2 * s);
  b = rr >> (7 - 2 * s);
  int chunk = rr & (perb - 1);
  int qg = (chunk << s) + (wv >> (3 - s));
  i0 = qg << 6;
  lo = (wv & (cpw - 1)) << 10;
  off = 16384 - (16384 >> s);
  alpha = 0.02f * (float)(1 << s);
}

// Stage per-thread list; group leader merges its qgroup's cpw lists.
template <int K>
__device__ __forceinline__ bool merge_group(float (&a)[K], float* sm,
                                            int tid, int cpw) {
  const int STR = K | 1;   // odd stride: 2-way bank aliasing only (free)
  int q = tid & 63, wv = tid >> 6;
  #pragma unroll
  for (int m = 0; m < K; ++m) sm[(wv * 64 + q) * STR + m] = a[m];
  __syncthreads();
  if (wv & (cpw - 1)) return false;
  for (int w = wv + 1; w < wv + cpw; ++w)
    #pragma unroll
    for (int m = 0; m < K; ++m)
      key_insert<K>(a, sm[(w * 64 + q) * STR + m]);
  return true;
}

// ---------- kernels ----------

// Init out/cnt/d2u AND build packed arrays {x,y,z,|c|2} for p2, p1, warp.
// 30720 threads; pack index t == b*NTOT + off + i by construction.
__global__ __launch_bounds__(256) void k_init(Params P) {
  int t = blockIdx.x * 256 + threadIdx.x;   // [0, 2*NTOT)
  if (t == 0) { P.out[0] = 0.f; *P.cnt = 1024u; }   // first tasks static
  P.d2u[t] = 0x7F7FFFFFu;                           // FLT_MAX bits
  int b = t >= NTOT;
  int r = t - b * NTOT;
  int s, i;
  if (r < 8192)       { s = 0; i = r; }
  else if (r < 12288) { s = 1; i = r - 8192; }
  else if (r < 14336) { s = 2; i = r - 12288; }
  else                { s = 3; i = r - 14336; }
  int N = 8192 >> s;
  const float* p2 = P.pc2[s] + b * 3 * N;
  const float* p1 = P.pc1[s] + b * 3 * N;
  const float* fl = P.fl[s] + b * 3 * N;
  float x2 = p2[i], y2 = p2[N + i], z2 = p2[2 * N + i];
  P.p2pk[t] = make_float4(x2, y2, z2, fmaf(x2, x2, fmaf(y2, y2, z2 * z2)));
  float x1 = p1[i], y1 = p1[N + i], z1 = p1[2 * N + i];
  P.p1pk[t] = make_float4(x1, y1, z1, fmaf(x1, x1, fmaf(y1, y1, z1 * z1)));
  float wx = x1 + fl[i], wy = y1 + fl[N + i], wz = z1 + fl[2 * N + i];
  P.wpk[t] = make_float4(wx, wy, wz, fmaf(wx, wx, fmaf(wy, wy, wz * wz)));
}

// Persistent blocks; task t: [0,340) A, [340,680) B, [680,1020) C,
// [1020,2380) D-micro ((s,b) from t ONLY -> SGPR-uniform pointers;
// 8 waves split within-batch wave-units u = ti*8 + wv).
__global__ __launch_bounds__(512, 8) void k_work(Params P) {
  __shared__ float sm[8 * 64 * 11];   // 22.5 KB merge staging
  __shared__ uint ts;
  int tid = threadIdx.x, q = tid & 63, wv = tid >> 6;
  uint vmask = MASKC;

  uint t = blockIdx.x;                // static first task, no pop burst
  while (t < NTASK) {
    if (t < 1020u) {
      int pass = (int)t / 340, r = (int)t % 340;
      int s, b, i0, lo, N, cpw, off; float alpha;
      decode(r, wv, s, b, i0, lo, N, cpw, off, alpha);
      int i = i0 + q;
      int lo_u = __builtin_amdgcn_readfirstlane(lo);

      if (pass == 0) {            // A: p2 self top-10 -> cv2
        const float4* cp = P.p2pk + b * NTOT + off;
        float4 qv = cp[i];
        float m2x = -2.f * qv.x, m2y = -2.f * qv.y, m2z = -2.f * qv.z;
        float a[10], bb[10];
        #pragma unroll
        for (int m = 0; m < 10; ++m) { a[m] = 3.0e38f; bb[m] = 3.0e38f; }
        scan_dot<10, false>(cp, lo_u, UNIT, m2x, m2y, m2z, qv.w, vmask,
                            a, bb);
        merge_pair<10>(a, bb);
        if (merge_group<10>(a, sm, tid, cpw)) {
          float sx = 0.f, sy = 0.f, sz = 0.f;
          #pragma unroll
          for (int m = 0; m < 10; ++m) {
            int j = (int)(__float_as_uint(a[m]) & 0x1FFFu);
            float4 cj = cp[j];
            sx += cj.x; sy += cj.y; sz += cj.z;
          }
          const float inv9 = 1.f / 9.f;
          P.cv2[b * NTOT + off + i] =
              make_float4((sx - 10.f * qv.x) * inv9,
                          (sy - 10.f * qv.y) * inv9,
                          (sz - 10.f * qv.z) * inv9, 0.f);
        }
      } else if (pass == 1) {     // B: p1 self top-10 -> cvw + smooth
        const float4* cp = P.p1pk + b * NTOT + off;
        const float* fl = P.fl[s] + b * 3 * N;
        float4 qv = cp[i];
        float m2x = -2.f * qv.x, m2y = -2.f * qv.y, m2z = -2.f * qv.z;
        float a[10], bb[10];
        #pragma unroll
        for (int m = 0; m < 10; ++m) { a[m] = 3.0e38f; bb[m] = 3.0e38f; }
        scan_dot<10, false>(cp, lo_u, UNIT, m2x, m2y, m2z, qv.w, vmask,
                            a, bb);
        merge_pair<10>(a, bb);
        if (merge_group<10>(a, sm, tid, cpw)) {
          float fix = fl[i], fiy = fl[N + i], fiz = fl[2 * N + i];
          float wix = qv.x + fix, wiy = qv.y + fiy, wiz = qv.z + fiz;
          float sx = 0.f, sy = 0.f, sz = 0.f, smooth = 0.f;
          float dmax = -1.f, worst = 0.f;
          #pragma unroll
          for (int m = 0; m < 10; ++m) {
            int j = (int)(__float_as_uint(a[m]) & 0x1FFFu);
            float4 cj = cp[j];
            float flx = fl[j], fly = fl[N + j], flz = fl[2 * N + j];
            sx += cj.x + flx; sy += cj.y + fly; sz += cj.z + flz;
            float ddx = cj.x - qv.x, ddy = cj.y - qv.y, ddz = cj.z - qv.z;
            float d = fmaf(ddx, ddx, fmaf(ddy, ddy, ddz * ddz));  // exact
            float gx = flx - fix, gy = fly - fiy, gz = flz - fiz;
            float term = sqrtf(fmaf(gx, gx, fmaf(gy, gy, gz * gz)));
            smooth += term;
            if (d > dmax) { dmax = d; worst = term; }  // drop farthest (k9)
          }
          smooth -= worst;
          const float inv9 = 1.f / 9.f;
          P.cvw[b * NTOT + off + i] = make_float4((sx - 10.f * wix) * inv9,
                                                  (sy - 10.f * wiy) * inv9,
                                                  (sz - 10.f * wiz) * inv9,
                                                  0.f);
          float ssum = wave_sum(smooth * (1.f / 8.f));
          if (q == 0) atomicAdd(P.out, alpha * 0.5f * ssum);
        }
      } else {                    // C: warp -> p2 top-5 -> packed keys
        const float4* cp = P.p2pk + b * NTOT + off;
        const float4* wq = P.wpk + b * NTOT + off;
        float4 qv = wq[i];
        float m2x = -2.f * qv.x, m2y = -2.f * qv.y, m2z = -2.f * qv.z;
        float a[5], bb[5];
        #pragma unroll
        for (int m = 0; m < 5; ++m) { a[m] = 3.0e38f; bb[m] = 3.0e38f; }
        scan_dot<5, false>(cp, lo_u, UNIT, m2x, m2y, m2z, qv.w, vmask,
                           a, bb);
        merge_pair<5>(a, bb);
        if (merge_group<5>(a, sm, tid, cpw)) {
          #pragma unroll
          for (int m = 0; m < 5; ++m)
            P.keys[m * (2 * NTOT) + b * NTOT + off + i] = a[m];
        }
      }
    } else {                      // D-micro: p2 -> warp min, atomicMin
      int dm = (int)(t - 1020u);
      int s, tb;
      if (dm < 1024)      { s = 0; tb = dm; }
      else if (dm < 1280) { s = 1; tb = dm - 1024; }
      else if (dm < 1344) { s = 2; tb = dm - 1280; }
      else                { s = 3; tb = dm - 1344; }
      int N = 8192 >> s;
      int tpb = 512 >> (2 * s);            // tasks per batch
      int b = tb >> (9 - 2 * s);
      int ti = tb & (tpb - 1);
      int u = ti * 8 + wv;                 // wave-unit within batch
      int rpq = 32 >> s;                   // 256-ranges per qgroup
      int qg = u >> (5 - s);
      int rg = u & (rpq - 1);
      int i = qg * 64 + q, lo = rg * 256;
      int off = 16384 - (16384 >> s);
      const float4* wc = P.wpk + b * NTOT + off;   // block-uniform cand
      const float4* qp = P.p2pk + b * NTOT + off;
      float4 qv = qp[i];
      float m2x = -2.f * qv.x, m2y = -2.f * qv.y, m2z = -2.f * qv.z;
      float a0[1], b0[1];
      a0[0] = 3.0e38f; b0[0] = 3.0e38f;
      int lo_u = __builtin_amdgcn_readfirstlane(lo);
      scan_dot<1, true>(wc, lo_u, 256, m2x, m2y, m2z, qv.w, vmask, a0, b0);
      atomicMin(P.d2u + b * NTOT + off + i,
                __float_as_uint(fminf(a0[0], b0[0])));
    }
    __syncthreads();              // sm + ts reuse safety
    if (tid == 0) ts = atomicAdd(P.cnt, 1u);
    __syncthreads();
    t = ts;
  }
}

// Epilogue: C top-5 -> exact dist1 + inverse-distance cv2 interp ->
// curvature; plus D partial-min sum. 30720 threads.
__global__ __launch_bounds__(256) void k_epi(Params P) {
  int t = blockIdx.x * 256 + threadIdx.x;   // [0, 2*NTOT)
  int b = t >= NTOT;
  int r = t - b * NTOT;
  int s, i;
  if (r < 8192)       { s = 0; i = r; }
  else if (r < 12288) { s = 1; i = r - 8192; }
  else if (r < 14336) { s = 2; i = r - 12288; }
  else                { s = 3; i = r - 14336; }
  int off = 16384 - (16384 >> s);
  float alpha = 0.02f * (float)(1 << s);
  const float4* cp = P.p2pk + b * NTOT + off;
  float4 qv = P.wpk[t];   // exact warp coords (same add as before)
  float ax = qv.x, ay = qv.y, az = qv.z;
  float dist1 = 3.0e38f, wsum = 0.f, ix = 0.f, iy = 0.f, iz = 0.f;
  #pragma unroll
  for (int m = 0; m < 5; ++m) {
    uint key = __float_as_uint(P.keys[m * (2 * NTOT) + b * NTOT + off + i]);
    int j = (int)(key & 0x1FFFu);
    float4 cj = cp[j];
    float ddx = cj.x - ax, ddy = cj.y - ay, ddz = cj.z - az;
    float d = fmaf(ddx, ddx, fmaf(ddy, ddy, ddz * ddz));  // exact
    dist1 = fminf(dist1, d);
    float w = 1.f / (d + 1e-8f);
    wsum += w;
    float4 cv = P.cv2[b * NTOT + off + j];
    ix += w * cv.x; iy += w * cv.y; iz += w * cv.z;
  }
  float inv = 1.f / wsum;
  ix *= inv; iy *= inv; iz *= inv;
  float4 cw = P.cvw[b * NTOT + off + i];
  float ex = ix - cw.x, ey = iy - cw.y, ez = iz - cw.z;
  float curv = fmaf(ex, ex, fmaf(ey, ey, ez * ez));
  float csum = wave_sum(dist1 + 0.3f * curv);
  float msum = wave_sum(__uint_as_float(P.d2u[t]));
  if ((threadIdx.x & 63) == 0) {
    atomicAdd(P.out, alpha * 0.5f * csum);
    atomicAdd(P.out, alpha * 0.5f * msum);
  }
}

extern "C" void kernel_launch(void* const* d_in, const int* in_sizes, int n_in,
                              void* d_out, int out_size, void* d_ws,
                              size_t ws_size, hipStream_t stream) {
  Params P;
  for (int s = 0; s < 4; ++s) {
    P.pc1[s] = (const float*)d_in[s];
    P.pc2[s] = (const float*)d_in[4 + s];
    P.fl[s]  = (const float*)d_in[8 + s];
  }
  char* ws = (char*)d_ws;
  P.cv2  = (float4*)ws;                    // 491520 B
  P.cvw  = (float4*)(ws + 491520);         // 491520 B
  P.keys = (float*)(ws + 983040);          // 614400 B
  P.d2u  = (uint*)(ws + 1597440);          // 122880 B
  P.cnt  = (uint*)(ws + 1720320);          // 64 B
  P.p2pk = (float4*)(ws + 1720384);        // 491520 B
  P.p1pk = (float4*)(ws + 2211904);        // 491520 B
  P.wpk  = (float4*)(ws + 2703424);        // 491520 B (end 3194944)
  P.out  = (float*)d_out;

  k_init<<<dim3(120), dim3(256), 0, stream>>>(P);
  k_work<<<dim3(1024), dim3(512), 0, stream>>>(P);
  k_epi<<<dim3(120), dim3(256), 0, stream>>>(P);
}

// Round 9
// 329.582 us; speedup vs baseline: 1.3601x; 1.2037x over previous
//
#include <hip/hip_runtime.h>
#include <math.h>

// PointPWC multi-scale loss. B=2, scales N={8192,4096,2048,1024}.
// Inputs (B,3,N) fp32 channel-major. Output: single fp32 scalar.
//
// R17: 2 queries per lane. Evidence chain: R16 (+33% candidate bytes ->
// +37% time), R14 (half transactions, same bytes -> -5%), R9~R10
// (mechanism swap -> 0%): the scan is scalar-cache BANDWIDTH bound
// (~1.2 B/cyc/CU for broadcast s_loads). Fix: each lane holds 2 queries
// (128-q group per 8-wave block) -> per candidate one wave serves 128
// pairs: K$ bytes/pair halved (below the wall), per-pair VALU unchanged,
// 4 independent insert chains/lane for ILP. Keys bit-identical (same
// fmaf dists, same chunk order, v_and_or pack proven in R16; top-K
// content is insert-order independent on unique keys).
// Schedule: 512 blocks (exactly 2/CU); heavy tasks A(170) B(170) C(170)
// statically owned by blocks 0..509 (R13's 1:1 heavy:resident balance),
// then 680 D-micro crumbs (128q x 256c, atomicMin) backfill the stagger.
// LDS merge: 22.5KB buffer reused sequentially (slot0, sync, slot1).

#define UNIT 1024
#define NTOT 15360
#define MASKC 0xFFFFE000u
#define NHEAVY 510u
#define NTASK 1190u   // 170 A + 170 B + 170 C + 680 D-micro

typedef unsigned int uint;
typedef __attribute__((ext_vector_type(16))) float f16v;

struct Params {
  const float* pc1[4];
  const float* pc2[4];
  const float* fl[4];
  float4* cv2;   // [B][NTOT]
  float4* cvw;   // [B][NTOT]
  float* keys;   // [5][B*NTOT] packed top-5 keys (pass C)
  uint* d2u;     // [B*NTOT] partial mins (pass D)
  uint* cnt;     // task queue counter
  float* warp;   // per-scale [B][3][N] warped p1 (= p1+fl)
  float* out;
};

// ---------- helpers ----------

__device__ __forceinline__ float wave_sum(float v) {
  #pragma unroll
  for (int o = 32; o; o >>= 1) v += __shfl_down(v, o, 64);
  return v;
}

template <int K>
__device__ __forceinline__ void key_insert(float (&kd)[K], float kf) {
  #pragma unroll
  for (int m = K - 1; m >= 1; --m)
    kd[m] = __builtin_amdgcn_fmed3f(kf, kd[m - 1], kd[m]);
  kd[0] = fminf(kd[0], kf);
}

template <int K>
__device__ __forceinline__ void merge_pair(float (&a)[K], const float (&b)[K]) {
  #pragma unroll
  for (int m = 0; m < K; ++m) key_insert<K>(a, b[m]);
}

// Wave-uniform broadcast of 16 candidates (3 planes, 12B/cand) into
// SGPRs. Loads + waitcnt fused in ONE asm block (SMEM completes
// out-of-order; only lgkmcnt(0) is safe). Pointers block-uniform.
__device__ __forceinline__ void sload3x16(const float* px, const float* py,
                                          const float* pz, int boff,
                                          f16v& x, f16v& y, f16v& z) {
  asm volatile(
      "s_load_dwordx16 %0, %3, %6\n\t"
      "s_load_dwordx16 %1, %4, %6\n\t"
      "s_load_dwordx16 %2, %5, %6\n\t"
      "s_waitcnt lgkmcnt(0)"
      : "=&s"(x), "=&s"(y), "=&s"(z)
      : "s"(px), "s"(py), "s"(pz), "s"(boff));
}

// Dual-query scan over [lo, lo+len). Even candidates -> a-chains, odd ->
// b-chains (same decomposition as R10..R16; top-K content is order-
// independent). Slot0 = query i, slot1 = query i+64.
template <int K, bool MIN>
__device__ void scan2(const float* px, const float* py, const float* pz,
                      int lo, int len, float ax0, float ay0, float az0,
                      float ax1, float ay1, float az1, uint vmask,
                      float (&a0)[K], float (&b0)[K],
                      float (&a1)[K], float (&b1)[K]) {
  #pragma unroll 1
  for (int c0 = 0; c0 < len; c0 += 16) {
    f16v xs, ys, zs;
    sload3x16(px, py, pz, (lo + c0) * 4, xs, ys, zs);
    #pragma unroll
    for (int t = 0; t < 16; ++t) {
      float X = xs[t], Y = ys[t], Z = zs[t];
      float dx0 = X - ax0, dy0 = Y - ay0, dz0 = Z - az0;
      float d0 = fmaf(dx0, dx0, fmaf(dy0, dy0, dz0 * dz0));
      float dx1 = X - ax1, dy1 = Y - ay1, dz1 = Z - az1;
      float d1 = fmaf(dx1, dx1, fmaf(dy1, dy1, dz1 * dz1));
      if (MIN) {
        if (t & 1) { b0[0] = fminf(b0[0], d0); b1[0] = fminf(b1[0], d1); }
        else       { a0[0] = fminf(a0[0], d0); a1[0] = fminf(a1[0], d1); }
      } else {
        uint idx = (uint)(lo + c0 + t);   // wave-uniform -> SGPR
        uint k0, k1;
        asm("v_and_or_b32 %0, %1, %2, %3" : "=v"(k0)
            : "v"(__float_as_uint(d0)), "v"(vmask), "s"(idx));
        asm("v_and_or_b32 %0, %1, %2, %3" : "=v"(k1)
            : "v"(__float_as_uint(d1)), "v"(vmask), "s"(idx));
        if (t & 1) {
          key_insert<K>(b0, __uint_as_float(k0));
          key_insert<K>(b1, __uint_as_float(k1));
        } else {
          key_insert<K>(a0, __uint_as_float(k0));
          key_insert<K>(a1, __uint_as_float(k1));
        }
      }
    }
  }
}

// Heavy-task decode: r in [0,170) -> scale s, batch b, 128-query-group
// base i0, candidate lo. Only i0/lo depend on wv; s,b block-uniform.
__device__ __forceinline__ void decode(int r, int wv, int& s, int& b,
                                       int& i0, int& lo, int& N, int& cpw,
                                       int& off, float& alpha) {
  int rr;
  if (r < 128)      { s = 0; rr = r; }
  else if (r < 160) { s = 1; rr = r - 128; }
  else if (r < 168) { s = 2; rr = r - 160; }
  else              { s = 3; rr = r - 168; }
  N = 8192 >> s;
  cpw = 8 >> s;
  int perb = 64 >> (2 * s);           // blocks per batch
  b = rr >> (6 - 2 * s);
  int chunk = rr & (perb - 1);
  int qg = (chunk << s) + (wv >> (3 - s));
  i0 = qg << 7;                       // 128-query groups
  lo = (wv & (cpw - 1)) << 10;
  off = 16384 - (16384 >> s);
  alpha = 0.02f * (float)(1 << s);
}

// Group-merge one query-slot's list through LDS (store, sync, leaders
// merge, sync). All threads call unconditionally -> uniform barriers;
// the trailing sync protects the buffer for the next slot's stores.
template <int K>
__device__ __forceinline__ void merge_slot(float (&a)[K], float* sm,
                                           int tid, int cpw, bool lead) {
  const int STR = K | 1;   // odd stride: 2-way bank aliasing only (free)
  int q = tid & 63, wv = tid >> 6;
  #pragma unroll
  for (int m = 0; m < K; ++m) sm[(wv * 64 + q) * STR + m] = a[m];
  __syncthreads();
  if (lead)
    for (int w = wv + 1; w < wv + cpw; ++w)
      #pragma unroll
      for (int m = 0; m < K; ++m)
        key_insert<K>(a, sm[(w * 64 + q) * STR + m]);
  __syncthreads();
}

// ---------- kernels ----------

// Init out/cnt/d2u AND precompute warp = p1+fl (flat per scale; same
// rounding as p1[j]+fl[j] -> bit-identical).
__global__ __launch_bounds__(256) void k_init(Params P) {
  int t = blockIdx.x * 256 + threadIdx.x;
  if (t == 0) { P.out[0] = 0.f; *P.cnt = 512u; }   // first tasks static
  if (t < 2 * NTOT) P.d2u[t] = 0x7F7FFFFFu;        // FLT_MAX bits
  int s, r;
  if (t < 49152)      { s = 0; r = t; }
  else if (t < 73728) { s = 1; r = t - 49152; }
  else if (t < 86016) { s = 2; r = t - 73728; }
  else if (t < 92160) { s = 3; r = t - 86016; }
  else return;
  int base6 = (s == 0) ? 0 : (s == 1) ? 49152 : (s == 2) ? 73728 : 86016;
  P.warp[base6 + r] = P.pc1[s][r] + P.fl[s][r];
}

// 512 persistent blocks (2/CU); task t: [0,170) A, [170,340) B,
// [340,510) C, [510,1190) D-micro ((s,b) from t ONLY; 8 waves split
// within-batch wave-units u = ti*8 + wv).
__global__ __launch_bounds__(512, 4) void k_work(Params P) {
  __shared__ float sm[8 * 64 * 11];   // 22.5 KB merge staging
  __shared__ uint ts;
  int tid = threadIdx.x, q = tid & 63, wv = tid >> 6;
  uint vmask = MASKC;

  uint t = blockIdx.x;                // blocks 0..509 own one heavy task
  while (t < NTASK) {
    if (t < NHEAVY) {
      int pass = (int)t / 170, r = (int)t % 170;
      int s, b, i0, lo, N, cpw, off; float alpha;
      decode(r, wv, s, b, i0, lo, N, cpw, off, alpha);
      int i = i0 + q, i2 = i0 + 64 + q;
      int lo_u = __builtin_amdgcn_readfirstlane(lo);
      bool lead = (wv & (cpw - 1)) == 0;

      if (pass == 0) {            // A: p2 self top-10 -> cv2
        const float* p2 = P.pc2[s] + b * 3 * N;
        float ax0 = p2[i], ay0 = p2[N + i], az0 = p2[2 * N + i];
        float ax1 = p2[i2], ay1 = p2[N + i2], az1 = p2[2 * N + i2];
        float a0[10], b0[10], a1[10], b1[10];
        #pragma unroll
        for (int m = 0; m < 10; ++m) {
          a0[m] = 3.0e38f; b0[m] = 3.0e38f;
          a1[m] = 3.0e38f; b1[m] = 3.0e38f;
        }
        scan2<10, false>(p2, p2 + N, p2 + 2 * N, lo_u, UNIT,
                         ax0, ay0, az0, ax1, ay1, az1, vmask,
                         a0, b0, a1, b1);
        merge_pair<10>(a0, b0);
        merge_pair<10>(a1, b1);
        merge_slot<10>(a0, sm, tid, cpw, lead);
        merge_slot<10>(a1, sm, tid, cpw, lead);
        if (lead) {
          const float inv9 = 1.f / 9.f;
          float sx = 0.f, sy = 0.f, sz = 0.f;
          #pragma unroll
          for (int m = 0; m < 10; ++m) {
            int j = (int)(__float_as_uint(a0[m]) & 0x1FFFu);
            sx += p2[j]; sy += p2[N + j]; sz += p2[2 * N + j];
          }
          P.cv2[b * NTOT + off + i] = make_float4((sx - 10.f * ax0) * inv9,
                                                  (sy - 10.f * ay0) * inv9,
                                                  (sz - 10.f * az0) * inv9,
                                                  0.f);
          sx = 0.f; sy = 0.f; sz = 0.f;
          #pragma unroll
          for (int m = 0; m < 10; ++m) {
            int j = (int)(__float_as_uint(a1[m]) & 0x1FFFu);
            sx += p2[j]; sy += p2[N + j]; sz += p2[2 * N + j];
          }
          P.cv2[b * NTOT + off + i2] = make_float4((sx - 10.f * ax1) * inv9,
                                                   (sy - 10.f * ay1) * inv9,
                                                   (sz - 10.f * az1) * inv9,
                                                   0.f);
        }
      } else if (pass == 1) {     // B: p1 self top-10 -> cvw + smooth
        const float* p1 = P.pc1[s] + b * 3 * N;
        const float* fl = P.fl[s] + b * 3 * N;
        float ax0 = p1[i], ay0 = p1[N + i], az0 = p1[2 * N + i];
        float ax1 = p1[i2], ay1 = p1[N + i2], az1 = p1[2 * N + i2];
        float a0[10], b0[10], a1[10], b1[10];
        #pragma unroll
        for (int m = 0; m < 10; ++m) {
          a0[m] = 3.0e38f; b0[m] = 3.0e38f;
          a1[m] = 3.0e38f; b1[m] = 3.0e38f;
        }
        scan2<10, false>(p1, p1 + N, p1 + 2 * N, lo_u, UNIT,
                         ax0, ay0, az0, ax1, ay1, az1, vmask,
                         a0, b0, a1, b1);
        merge_pair<10>(a0, b0);
        merge_pair<10>(a1, b1);
        merge_slot<10>(a0, sm, tid, cpw, lead);
        merge_slot<10>(a1, sm, tid, cpw, lead);
        float ssum_l = 0.f;
        if (lead) {
          const float inv9 = 1.f / 9.f;
          // slot 0 (query i)
          {
            float fix = fl[i], fiy = fl[N + i], fiz = fl[2 * N + i];
            float wix = ax0 + fix, wiy = ay0 + fiy, wiz = az0 + fiz;
            float sx = 0.f, sy = 0.f, sz = 0.f, smooth = 0.f;
            float dmax = -1.f, worst = 0.f;
            #pragma unroll
            for (int m = 0; m < 10; ++m) {
              int j = (int)(__float_as_uint(a0[m]) & 0x1FFFu);
              float px = p1[j], py = p1[N + j], pz = p1[2 * N + j];
              float flx = fl[j], fly = fl[N + j], flz = fl[2 * N + j];
              sx += px + flx; sy += py + fly; sz += pz + flz;
              float ddx = px - ax0, ddy = py - ay0, ddz = pz - az0;
              float d = fmaf(ddx, ddx, fmaf(ddy, ddy, ddz * ddz));
              float gx = flx - fix, gy = fly - fiy, gz = flz - fiz;
              float term = sqrtf(fmaf(gx, gx, fmaf(gy, gy, gz * gz)));
              smooth += term;
              if (d > dmax) { dmax = d; worst = term; }  // drop farthest
            }
            smooth -= worst;
            P.cvw[b * NTOT + off + i] =
                make_float4((sx - 10.f * wix) * inv9,
                            (sy - 10.f * wiy) * inv9,
                            (sz - 10.f * wiz) * inv9, 0.f);
            ssum_l += smooth;
          }
          // slot 1 (query i2)
          {
            float fix = fl[i2], fiy = fl[N + i2], fiz = fl[2 * N + i2];
            float wix = ax1 + fix, wiy = ay1 + fiy, wiz = az1 + fiz;
            float sx = 0.f, sy = 0.f, sz = 0.f, smooth = 0.f;
            float dmax = -1.f, worst = 0.f;
            #pragma unroll
            for (int m = 0; m < 10; ++m) {
              int j = (int)(__float_as_uint(a1[m]) & 0x1FFFu);
              float px = p1[j], py = p1[N + j], pz = p1[2 * N + j];
              float flx = fl[j], fly = fl[N + j], flz = fl[2 * N + j];
              sx += px + flx; sy += py + fly; sz += pz + flz;
              float ddx = px - ax1, ddy = py - ay1, ddz = pz - az1;
              float d = fmaf(ddx, ddx, fmaf(ddy, ddy, ddz * ddz));
              float gx = flx - fix, gy = fly - fiy, gz = flz - fiz;
              float term = sqrtf(fmaf(gx, gx, fmaf(gy, gy, gz * gz)));
              smooth += term;
              if (d > dmax) { dmax = d; worst = term; }
            }
            smooth -= worst;
            P.cvw[b * NTOT + off + i2] =
                make_float4((sx - 10.f * wix) * inv9,
                            (sy - 10.f * wiy) * inv9,
                            (sz - 10.f * wiz) * inv9, 0.f);
            ssum_l += smooth;
          }
          float ssum = wave_sum(ssum_l * (1.f / 8.f));
          if (q == 0) atomicAdd(P.out, alpha * 0.5f * ssum);
        }
      } else {                    // C: warp -> p2 top-5 -> packed keys
        int base6 = (s == 0) ? 0 : (s == 1) ? 49152 : (s == 2) ? 73728
                                                               : 86016;
        const float* wq = P.warp + base6 + b * 3 * N;
        const float* p2 = P.pc2[s] + b * 3 * N;
        float ax0 = wq[i], ay0 = wq[N + i], az0 = wq[2 * N + i];
        float ax1 = wq[i2], ay1 = wq[N + i2], az1 = wq[2 * N + i2];
        float a0[5], b0[5], a1[5], b1[5];
        #pragma unroll
        for (int m = 0; m < 5; ++m) {
          a0[m] = 3.0e38f; b0[m] = 3.0e38f;
          a1[m] = 3.0e38f; b1[m] = 3.0e38f;
        }
        scan2<5, false>(p2, p2 + N, p2 + 2 * N, lo_u, UNIT,
                        ax0, ay0, az0, ax1, ay1, az1, vmask,
                        a0, b0, a1, b1);
        merge_pair<5>(a0, b0);
        merge_pair<5>(a1, b1);
        merge_slot<5>(a0, sm, tid, cpw, lead);
        merge_slot<5>(a1, sm, tid, cpw, lead);
        if (lead) {
          #pragma unroll
          for (int m = 0; m < 5; ++m) {
            P.keys[m * (2 * NTOT) + b * NTOT + off + i] = a0[m];
            P.keys[m * (2 * NTOT) + b * NTOT + off + i2] = a1[m];
          }
        }
      }
    } else {                      // D-micro: p2 -> warp min, atomicMin
      int dm = (int)(t - NHEAVY);
      int s, tb;
      if (dm < 512)      { s = 0; tb = dm; }
      else if (dm < 640) { s = 1; tb = dm - 512; }
      else if (dm < 672) { s = 2; tb = dm - 640; }
      else               { s = 3; tb = dm - 672; }
      int N = 8192 >> s;
      int tpb = 256 >> (2 * s);            // tasks per batch
      int b = tb >> (8 - 2 * s);
      int ti = tb & (tpb - 1);
      int u = ti * 8 + wv;                 // wave-unit within batch
      int rgc = 32 >> s;                   // 256-ranges per batch dim
      int qg = u >> (5 - s);               // u / rgc
      int rg = u & (rgc - 1);
      int i = qg * 128 + q, i2 = i + 64, lo = rg * 256;
      int off = 16384 - (16384 >> s);
      int base6 = (s == 0) ? 0 : (s == 1) ? 49152 : (s == 2) ? 73728
                                                             : 86016;
      const float* wc = P.warp + base6 + b * 3 * N;  // block-uniform
      const float* p2 = P.pc2[s] + b * 3 * N;
      float ax0 = p2[i], ay0 = p2[N + i], az0 = p2[2 * N + i];
      float ax1 = p2[i2], ay1 = p2[N + i2], az1 = p2[2 * N + i2];
      float a0[1], b0[1], a1[1], b1[1];
      a0[0] = 3.0e38f; b0[0] = 3.0e38f; a1[0] = 3.0e38f; b1[0] = 3.0e38f;
      int lo_u = __builtin_amdgcn_readfirstlane(lo);
      scan2<1, true>(wc, wc + N, wc + 2 * N, lo_u, 256,
                     ax0, ay0, az0, ax1, ay1, az1, vmask,
                     a0, b0, a1, b1);
      atomicMin(P.d2u + b * NTOT + off + i,
                __float_as_uint(fminf(a0[0], b0[0])));
      atomicMin(P.d2u + b * NTOT + off + i2,
                __float_as_uint(fminf(a1[0], b1[0])));
    }
    __syncthreads();              // sm + ts reuse safety
    if (tid == 0) ts = atomicAdd(P.cnt, 1u);
    __syncthreads();
    t = ts;
  }
}

// Epilogue: C top-5 -> exact dist1 + inverse-distance cv2 interp ->
// curvature; plus D partial-min sum. 30720 threads.
__global__ __launch_bounds__(256) void k_epi(Params P) {
  int t = blockIdx.x * 256 + threadIdx.x;   // [0, 2*NTOT)
  int b = t >= NTOT;
  int r = t - b * NTOT;
  int s, i;
  if (r < 8192)       { s = 0; i = r; }
  else if (r < 12288) { s = 1; i = r - 8192; }
  else if (r < 14336) { s = 2; i = r - 12288; }
  else                { s = 3; i = r - 14336; }
  int N = 8192 >> s;
  int off = 16384 - (16384 >> s);
  float alpha = 0.02f * (float)(1 << s);
  const float* p1 = P.pc1[s] + b * 3 * N;
  const float* fl = P.fl[s] + b * 3 * N;
  const float* p2 = P.pc2[s] + b * 3 * N;
  float ax = p1[i] + fl[i], ay = p1[N + i] + fl[N + i],
        az = p1[2 * N + i] + fl[2 * N + i];
  float dist1 = 3.0e38f, wsum = 0.f, ix = 0.f, iy = 0.f, iz = 0.f;
  #pragma unroll
  for (int m = 0; m < 5; ++m) {
    uint key = __float_as_uint(P.keys[m * (2 * NTOT) + b * NTOT + off + i]);
    int j = (int)(key & 0x1FFFu);
    float px = p2[j], py = p2[N + j], pz = p2[2 * N + j];
    float ddx = px - ax, ddy = py - ay, ddz = pz - az;
    float d = fmaf(ddx, ddx, fmaf(ddy, ddy, ddz * ddz));  // exact
    dist1 = fminf(dist1, d);
    float w = 1.f / (d + 1e-8f);
    wsum += w;
    float4 cv = P.cv2[b * NTOT + off + j];
    ix += w * cv.x; iy += w * cv.y; iz += w * cv.z;
  }
  float inv = 1.f / wsum;
  ix *= inv; iy *= inv; iz *= inv;
  float4 cw = P.cvw[b * NTOT + off + i];
  float ex = ix - cw.x, ey = iy - cw.y, ez = iz - cw.z;
  float curv = fmaf(ex, ex, fmaf(ey, ey, ez * ez));
  float csum = wave_sum(dist1 + 0.3f * curv);
  float msum = wave_sum(__uint_as_float(P.d2u[t]));
  if ((threadIdx.x & 63) == 0) {
    atomicAdd(P.out, alpha * 0.5f * csum);
    atomicAdd(P.out, alpha * 0.5f * msum);
  }
}

extern "C" void kernel_launch(void* const* d_in, const int* in_sizes, int n_in,
                              void* d_out, int out_size, void* d_ws,
                              size_t ws_size, hipStream_t stream) {
  Params P;
  for (int s = 0; s < 4; ++s) {
    P.pc1[s] = (const float*)d_in[s];
    P.pc2[s] = (const float*)d_in[4 + s];
    P.fl[s]  = (const float*)d_in[8 + s];
  }
  char* ws = (char*)d_ws;
  P.cv2  = (float4*)ws;                    // 491520 B
  P.cvw  = (float4*)(ws + 491520);         // 491520 B
  P.keys = (float*)(ws + 983040);          // 614400 B
  P.d2u  = (uint*)(ws + 1597440);          // 122880 B
  P.cnt  = (uint*)(ws + 1720320);          // 64 B
  P.warp = (float*)(ws + 1720384);         // 368640 B (total 2089024)
  P.out  = (float*)d_out;

  k_init<<<dim3(360), dim3(256), 0, stream>>>(P);
  k_work<<<dim3(512), dim3(512), 0, stream>>>(P);
  k_epi<<<dim3(120), dim3(256), 0, stream>>>(P);
}

// Round 10
// 289.961 us; speedup vs baseline: 1.5460x; 1.1366x over previous
//
#include <hip/hip_runtime.h>
#include <math.h>

// PointPWC multi-scale loss. B=2, scales N={8192,4096,2048,1024}.
// Inputs (B,3,N) fp32 channel-major. Output: single fp32 scalar.
//
// R18 = R14 k_work verbatim (best: 244us, SMEM x16 broadcast, 12B/cand,
// persistent 1024 blocks, A/B/C heavy + 1360 D-micro fillers)
//      + k_epi atomic fix.
// Gap analysis across rounds: bench_total - sum(dispatches) = ~3us in R8
// (no k_epi) but 41-62us in R9..R17 (with k_epi) -> the 30K-thread
// epilogue costs ~50us, 20x its arithmetic. Cause: 960 same-address
// atomicAdd RMWs to P.out (480 waves x 2), serialized in L2 at ~100ns
// each; R8 hid them behind 200us of co-resident compute, k_epi exposes
// them. Fix: per-wave partials -> LDS -> thread 0 -> ONE atomicAdd per
// block (120 total). k_work's ~500 B-pass atomics stay hidden behind
// 244us. R17 lesson (2q/lane at 2 blocks/CU: +10%) also falsifies K$-BW
// as the k_work wall; R14 remains the empirical best k_work config.

#define UNIT 1024
#define NTOT 15360
#define MASKC 0xFFFFE000u
#define NTASK 2380u   // 340 A + 340 B + 340 C + 1360 D-micro

typedef unsigned int uint;
typedef __attribute__((ext_vector_type(16))) float f16v;

struct Params {
  const float* pc1[4];
  const float* pc2[4];
  const float* fl[4];
  float4* cv2;   // [B][NTOT]
  float4* cvw;   // [B][NTOT]
  float* keys;   // [5][B*NTOT] packed top-5 keys (pass C)
  uint* d2u;     // [B*NTOT] partial mins (pass D)
  uint* cnt;     // task queue counter
  float* warp;   // per-scale [B][3][N] warped p1 (= p1+fl)
  float* out;
};

// ---------- helpers ----------

__device__ __forceinline__ float wave_sum(float v) {
  #pragma unroll
  for (int o = 32; o; o >>= 1) v += __shfl_down(v, o, 64);
  return v;
}

template <int K>
__device__ __forceinline__ void key_insert(float (&kd)[K], float kf) {
  #pragma unroll
  for (int m = K - 1; m >= 1; --m)
    kd[m] = __builtin_amdgcn_fmed3f(kf, kd[m - 1], kd[m]);
  kd[0] = fminf(kd[0], kf);
}

template <int K>
__device__ __forceinline__ void merge_pair(float (&a)[K], const float (&b)[K]) {
  #pragma unroll
  for (int m = 0; m < K; ++m) key_insert<K>(a, b[m]);
}

__device__ __forceinline__ float pack_key_u(float d, uint iw) {
  return __uint_as_float((__float_as_uint(d) & MASKC) | iw);
}

// Wave-uniform broadcast of 16 candidates (3 planes, 12B/cand) into
// SGPRs. Loads + waitcnt fused in ONE asm block (SMEM completes
// out-of-order; only lgkmcnt(0) is safe; split issue/wait risks copies
// of in-flight regs). Pointers must be block-uniform for "s" to hold.
__device__ __forceinline__ void sload3x16(const float* px, const float* py,
                                          const float* pz, int boff,
                                          f16v& x, f16v& y, f16v& z) {
  asm volatile(
      "s_load_dwordx16 %0, %3, %6\n\t"
      "s_load_dwordx16 %1, %4, %6\n\t"
      "s_load_dwordx16 %2, %5, %6\n\t"
      "s_waitcnt lgkmcnt(0)"
      : "=&s"(x), "=&s"(y), "=&s"(z)
      : "s"(px), "s"(py), "s"(pz), "s"(boff));
}

// Top-K scan over [lo, lo+UNIT); candidates from SGPRs. Two chains.
template <int K>
__device__ void scan_k(const float* px, const float* py, const float* pz,
                       int lo, float ax, float ay, float az,
                       float (&a)[K], float (&b)[K]) {
  #pragma unroll 1
  for (int c0 = 0; c0 < UNIT; c0 += 16) {
    f16v xs, ys, zs;
    sload3x16(px, py, pz, (lo + c0) * 4, xs, ys, zs);
    #pragma unroll
    for (int t = 0; t < 16; t += 2) {
      float dxa = xs[t] - ax, dya = ys[t] - ay, dza = zs[t] - az;
      float dA = fmaf(dxa, dxa, fmaf(dya, dya, dza * dza));
      float dxb = xs[t + 1] - ax, dyb = ys[t + 1] - ay, dzb = zs[t + 1] - az;
      float dB = fmaf(dxb, dxb, fmaf(dyb, dyb, dzb * dzb));
      key_insert<K>(a, pack_key_u(dA, (uint)(lo + c0 + t)));
      key_insert<K>(b, pack_key_u(dB, (uint)(lo + c0 + t + 1)));
    }
  }
}

// Min-only scan over [lo, lo+len): candidates from SGPRs (pass D uses
// precomputed warp -> 7 VALU/candidate).
__device__ void scan_m(const float* px, const float* py, const float* pz,
                       int lo, int len, float ax, float ay, float az,
                       float& a0, float& b0) {
  #pragma unroll 1
  for (int c0 = 0; c0 < len; c0 += 16) {
    f16v xs, ys, zs;
    sload3x16(px, py, pz, (lo + c0) * 4, xs, ys, zs);
    #pragma unroll
    for (int t = 0; t < 16; t += 2) {
      float dxa = xs[t] - ax, dya = ys[t] - ay, dza = zs[t] - az;
      float dA = fmaf(dxa, dxa, fmaf(dya, dya, dza * dza));
      float dxb = xs[t + 1] - ax, dyb = ys[t + 1] - ay, dzb = zs[t + 1] - az;
      float dB = fmaf(dxb, dxb, fmaf(dyb, dyb, dzb * dzb));
      a0 = fminf(a0, dA);
      b0 = fminf(b0, dB);
    }
  }
}

// r in [0,340) -> scale s, batch b, query-group base i0, candidate lo.
// Only i0/lo depend on wv; s,b are block-uniform.
__device__ __forceinline__ void decode(int r, int wv, int& s, int& b,
                                       int& i0, int& lo, int& N, int& cpw,
                                       int& off, float& alpha) {
  int rr;
  if (r < 256)      { s = 0; rr = r; }
  else if (r < 320) { s = 1; rr = r - 256; }
  else if (r < 336) { s = 2; rr = r - 320; }
  else              { s = 3; rr = r - 336; }
  N = 8192 >> s;
  cpw = 8 >> s;
  int perb = 128 >> (2 * s);
  b = rr >> (7 - 2 * s);
  int chunk = rr & (perb - 1);
  int qg = (chunk << s) + (wv >> (3 - s));
  i0 = qg << 6;
  lo = (wv & (cpw - 1)) << 10;
  off = 16384 - (16384 >> s);
  alpha = 0.02f * (float)(1 << s);
}

// Stage per-thread list; group leader (wave with cr==0) merges its
// qgroup's cpw lists. Returns true for leader threads.
template <int K>
__device__ __forceinline__ bool merge_group(float (&a)[K], float* sm,
                                            int tid, int cpw) {
  const int STR = K | 1;   // odd stride: 2-way bank aliasing only (free)
  int q = tid & 63, wv = tid >> 6;
  #pragma unroll
  for (int m = 0; m < K; ++m) sm[(wv * 64 + q) * STR + m] = a[m];
  __syncthreads();
  if (wv & (cpw - 1)) return false;
  for (int w = wv + 1; w < wv + cpw; ++w)
    #pragma unroll
    for (int m = 0; m < K; ++m)
      key_insert<K>(a, sm[(w * 64 + q) * STR + m]);
  return true;
}

// ---------- kernels ----------

// Init scalars/d2u AND precompute warp = p1+fl (flat per scale; same
// rounding as the p1[j]+fl[j] it replaces -> bit-identical).
__global__ __launch_bounds__(256) void k_init(Params P) {
  int t = blockIdx.x * 256 + threadIdx.x;
  if (t == 0) { P.out[0] = 0.f; *P.cnt = 1024u; }   // first tasks static
  if (t < 2 * NTOT) P.d2u[t] = 0x7F7FFFFFu;         // FLT_MAX bits
  int s, r;
  if (t < 49152)      { s = 0; r = t; }
  else if (t < 73728) { s = 1; r = t - 49152; }
  else if (t < 86016) { s = 2; r = t - 73728; }
  else if (t < 92160) { s = 3; r = t - 86016; }
  else return;
  int base6 = (s == 0) ? 0 : (s == 1) ? 49152 : (s == 2) ? 73728 : 86016;
  P.warp[base6 + r] = P.pc1[s][r] + P.fl[s][r];
}

// Persistent blocks; task t: [0,340) A, [340,680) B, [680,1020) C,
// [1020,2380) D-micro ((s,b) from t ONLY -> SGPR-uniform base pointers;
// 8 waves split within-batch wave-units u = ti*8 + wv).
__global__ __launch_bounds__(512, 8) void k_work(Params P) {
  __shared__ float sm[8 * 64 * 11];   // 22.5 KB merge staging
  __shared__ uint ts;
  int tid = threadIdx.x, q = tid & 63, wv = tid >> 6;

  uint t = blockIdx.x;                // static first task, no pop burst
  while (t < NTASK) {
    if (t < 1020u) {
      int pass = (int)t / 340, r = (int)t % 340;
      int s, b, i0, lo, N, cpw, off; float alpha;
      decode(r, wv, s, b, i0, lo, N, cpw, off, alpha);
      int i = i0 + q;
      int lo_u = __builtin_amdgcn_readfirstlane(lo);

      if (pass == 0) {            // A: p2 self top-10 -> cv2
        const float* p2 = P.pc2[s] + b * 3 * N;
        float ax = p2[i], ay = p2[N + i], az = p2[2 * N + i];
        float a[10], bb[10];
        #pragma unroll
        for (int m = 0; m < 10; ++m) { a[m] = 3.0e38f; bb[m] = 3.0e38f; }
        scan_k<10>(p2, p2 + N, p2 + 2 * N, lo_u, ax, ay, az, a, bb);
        merge_pair<10>(a, bb);
        if (merge_group<10>(a, sm, tid, cpw)) {
          float sx = 0.f, sy = 0.f, sz = 0.f;
          #pragma unroll
          for (int m = 0; m < 10; ++m) {
            int j = (int)(__float_as_uint(a[m]) & 0x1FFFu);
            sx += p2[j]; sy += p2[N + j]; sz += p2[2 * N + j];
          }
          const float inv9 = 1.f / 9.f;
          P.cv2[b * NTOT + off + i] = make_float4((sx - 10.f * ax) * inv9,
                                                  (sy - 10.f * ay) * inv9,
                                                  (sz - 10.f * az) * inv9,
                                                  0.f);
        }
      } else if (pass == 1) {     // B: p1 self top-10 -> cvw + smooth
        const float* p1 = P.pc1[s] + b * 3 * N;
        const float* fl = P.fl[s] + b * 3 * N;
        float ax = p1[i], ay = p1[N + i], az = p1[2 * N + i];
        float a[10], bb[10];
        #pragma unroll
        for (int m = 0; m < 10; ++m) { a[m] = 3.0e38f; bb[m] = 3.0e38f; }
        scan_k<10>(p1, p1 + N, p1 + 2 * N, lo_u, ax, ay, az, a, bb);
        merge_pair<10>(a, bb);
        if (merge_group<10>(a, sm, tid, cpw)) {
          float fix = fl[i], fiy = fl[N + i], fiz = fl[2 * N + i];
          float wix = ax + fix, wiy = ay + fiy, wiz = az + fiz;
          float sx = 0.f, sy = 0.f, sz = 0.f, smooth = 0.f;
          float dmax = -1.f, worst = 0.f;
          #pragma unroll
          for (int m = 0; m < 10; ++m) {
            int j = (int)(__float_as_uint(a[m]) & 0x1FFFu);
            float px = p1[j], py = p1[N + j], pz = p1[2 * N + j];
            float flx = fl[j], fly = fl[N + j], flz = fl[2 * N + j];
            sx += px + flx; sy += py + fly; sz += pz + flz;
            float ddx = px - ax, ddy = py - ay, ddz = pz - az;
            float d = fmaf(ddx, ddx, fmaf(ddy, ddy, ddz * ddz));  // exact
            float gx = flx - fix, gy = fly - fiy, gz = flz - fiz;
            float term = sqrtf(fmaf(gx, gx, fmaf(gy, gy, gz * gz)));
            smooth += term;
            if (d > dmax) { dmax = d; worst = term; }  // drop farthest (k9)
          }
          smooth -= worst;
          const float inv9 = 1.f / 9.f;
          P.cvw[b * NTOT + off + i] = make_float4((sx - 10.f * wix) * inv9,
                                                  (sy - 10.f * wiy) * inv9,
                                                  (sz - 10.f * wiz) * inv9,
                                                  0.f);
          float ssum = wave_sum(smooth * (1.f / 8.f));
          if (q == 0) atomicAdd(P.out, alpha * 0.5f * ssum);
        }
      } else {                    // C: warp -> p2 top-5 -> packed keys
        int base6 = (s == 0) ? 0 : (s == 1) ? 49152 : (s == 2) ? 73728
                                                               : 86016;
        const float* wq = P.warp + base6 + b * 3 * N;
        const float* p2 = P.pc2[s] + b * 3 * N;
        float ax = wq[i], ay = wq[N + i], az = wq[2 * N + i];  // == p1+fl
        float a[5], bb[5];
        #pragma unroll
        for (int m = 0; m < 5; ++m) { a[m] = 3.0e38f; bb[m] = 3.0e38f; }
        scan_k<5>(p2, p2 + N, p2 + 2 * N, lo_u, ax, ay, az, a, bb);
        merge_pair<5>(a, bb);
        if (merge_group<5>(a, sm, tid, cpw)) {
          #pragma unroll
          for (int m = 0; m < 5; ++m)
            P.keys[m * (2 * NTOT) + b * NTOT + off + i] = a[m];
        }
      }
    } else {                      // D-micro: p2 -> warp min, atomicMin
      int dm = (int)(t - 1020u);
      int s, tb;
      if (dm < 1024)      { s = 0; tb = dm; }
      else if (dm < 1280) { s = 1; tb = dm - 1024; }
      else if (dm < 1344) { s = 2; tb = dm - 1280; }
      else                { s = 3; tb = dm - 1344; }
      int N = 8192 >> s;
      int tpb = 512 >> (2 * s);            // tasks per batch
      int b = tb >> (9 - 2 * s);
      int ti = tb & (tpb - 1);
      int u = ti * 8 + wv;                 // wave-unit within batch
      int rpq = 32 >> s;                   // 256-ranges per qgroup
      int qg = u >> (5 - s);
      int rg = u & (rpq - 1);
      int i = qg * 64 + q, lo = rg * 256;
      int off = 16384 - (16384 >> s);
      int base6 = (s == 0) ? 0 : (s == 1) ? 49152 : (s == 2) ? 73728
                                                             : 86016;
      const float* wc = P.warp + base6 + b * 3 * N;  // block-uniform
      const float* p2 = P.pc2[s] + b * 3 * N;
      float ax = p2[i], ay = p2[N + i], az = p2[2 * N + i];
      float a0 = 3.0e38f, b0 = 3.0e38f;
      int lo_u = __builtin_amdgcn_readfirstlane(lo);
      scan_m(wc, wc + N, wc + 2 * N, lo_u, 256, ax, ay, az, a0, b0);
      atomicMin(P.d2u + b * NTOT + off + i, __float_as_uint(fminf(a0, b0)));
    }
    __syncthreads();              // sm + ts reuse safety
    if (tid == 0) ts = atomicAdd(P.cnt, 1u);
    __syncthreads();
    t = ts;
  }
}

// Epilogue: C top-5 -> exact dist1 + inverse-distance cv2 interp ->
// curvature; plus D partial-min sum. 30720 threads.
// R18: per-wave partials -> LDS -> ONE atomicAdd per block (120 total
// vs 960 same-address RMWs that cost ~50us exposed).
__global__ __launch_bounds__(256) void k_epi(Params P) {
  __shared__ float part[8];
  int t = blockIdx.x * 256 + threadIdx.x;   // [0, 2*NTOT)
  int b = t >= NTOT;
  int r = t - b * NTOT;
  int s, i;
  if (r < 8192)       { s = 0; i = r; }
  else if (r < 12288) { s = 1; i = r - 8192; }
  else if (r < 14336) { s = 2; i = r - 12288; }
  else                { s = 3; i = r - 14336; }
  int N = 8192 >> s;
  int off = 16384 - (16384 >> s);
  float alpha = 0.02f * (float)(1 << s);
  const float* p1 = P.pc1[s] + b * 3 * N;
  const float* fl = P.fl[s] + b * 3 * N;
  const float* p2 = P.pc2[s] + b * 3 * N;
  float ax = p1[i] + fl[i], ay = p1[N + i] + fl[N + i],
        az = p1[2 * N + i] + fl[2 * N + i];
  float dist1 = 3.0e38f, wsum = 0.f, ix = 0.f, iy = 0.f, iz = 0.f;
  #pragma unroll
  for (int m = 0; m < 5; ++m) {
    uint key = __float_as_uint(P.keys[m * (2 * NTOT) + b * NTOT + off + i]);
    int j = (int)(key & 0x1FFFu);
    float px = p2[j], py = p2[N + j], pz = p2[2 * N + j];
    float ddx = px - ax, ddy = py - ay, ddz = pz - az;
    float d = fmaf(ddx, ddx, fmaf(ddy, ddy, ddz * ddz));  // exact
    dist1 = fminf(dist1, d);
    float w = 1.f / (d + 1e-8f);
    wsum += w;
    float4 cv = P.cv2[b * NTOT + off + j];
    ix += w * cv.x; iy += w * cv.y; iz += w * cv.z;
  }
  float inv = 1.f / wsum;
  ix *= inv; iy *= inv; iz *= inv;
  float4 cw = P.cvw[b * NTOT + off + i];
  float ex = ix - cw.x, ey = iy - cw.y, ez = iz - cw.z;
  float curv = fmaf(ex, ex, fmaf(ey, ey, ez * ez));
  float csum = wave_sum(dist1 + 0.3f * curv);
  float msum = wave_sum(__uint_as_float(P.d2u[t]));
  int wv = threadIdx.x >> 6;
  if ((threadIdx.x & 63) == 0) {
    part[wv] = alpha * 0.5f * csum;       // alpha is wave-uniform
    part[4 + wv] = alpha * 0.5f * msum;
  }
  __syncthreads();
  if (threadIdx.x == 0) {
    float v = 0.f;
    #pragma unroll
    for (int m = 0; m < 8; ++m) v += part[m];
    atomicAdd(P.out, v);
  }
}

extern "C" void kernel_launch(void* const* d_in, const int* in_sizes, int n_in,
                              void* d_out, int out_size, void* d_ws,
                              size_t ws_size, hipStream_t stream) {
  Params P;
  for (int s = 0; s < 4; ++s) {
    P.pc1[s] = (const float*)d_in[s];
    P.pc2[s] = (const float*)d_in[4 + s];
    P.fl[s]  = (const float*)d_in[8 + s];
  }
  char* ws = (char*)d_ws;
  P.cv2  = (float4*)ws;                    // 491520 B
  P.cvw  = (float4*)(ws + 491520);         // 491520 B
  P.keys = (float*)(ws + 983040);          // 614400 B
  P.d2u  = (uint*)(ws + 1597440);          // 122880 B
  P.cnt  = (uint*)(ws + 1720320);          // 64 B
  P.warp = (float*)(ws + 1720384);         // 368640 B (total 2089024)
  P.out  = (float*)d_out;

  k_init<<<dim3(360), dim3(256), 0, stream>>>(P);
  k_work<<<dim3(1024), dim3(512), 0, stream>>>(P);
  k_epi<<<dim3(120), dim3(256), 0, stream>>>(P);
}